// Round 8
// baseline (511.413 us; speedup 1.0000x reference)
//
#include <hip/hip_runtime.h>
#include <hip/hip_bf16.h>

#define N_NODES 8192
#define D_DIM   256

typedef __attribute__((ext_vector_type(8))) short short8v;   // 8 x bf16 (4 VGPR)
typedef __attribute__((ext_vector_type(4))) float f32x4;

__device__ __forceinline__ float artanh_clip(float x) {
    x = fminf(x, 1.0f - 1e-7f);
    return 0.5f * logf((1.0f + x) / (1.0f - x));
}

__device__ __forceinline__ short8v cvt8_bf16(float4 lo, float4 hi) {
    union { ushort u[8]; short8v v; } r;
    r.u[0] = __bfloat16_as_ushort(__float2bfloat16(lo.x));
    r.u[1] = __bfloat16_as_ushort(__float2bfloat16(lo.y));
    r.u[2] = __bfloat16_as_ushort(__float2bfloat16(lo.z));
    r.u[3] = __bfloat16_as_ushort(__float2bfloat16(lo.w));
    r.u[4] = __bfloat16_as_ushort(__float2bfloat16(hi.x));
    r.u[5] = __bfloat16_as_ushort(__float2bfloat16(hi.y));
    r.u[6] = __bfloat16_as_ushort(__float2bfloat16(hi.z));
    r.u[7] = __bfloat16_as_ushort(__float2bfloat16(hi.w));
    return r.v;
}

__device__ __forceinline__ void nt_store4(float4 v, float* p) {
    f32x4 w = {v.x, v.y, v.z, v.w};
    __builtin_nontemporal_store(w, (f32x4*)p);
}

// ---------------- K0: hyp_bias = proj(expmap0(bias)), plus b2 = ||hb||^2 ----
__global__ void k0_bias(const float* __restrict__ bias, float* __restrict__ hbg) {
    __shared__ float sp[4];
    __shared__ float s_g;
    int t = threadIdx.x;
    float u = bias[t];
    float v = u * u;
    #pragma unroll
    for (int o = 1; o < 64; o <<= 1) v += __shfl_xor(v, o);
    if ((t & 63) == 0) sp[t >> 6] = v;
    __syncthreads();
    if (t == 0) {
        float s  = sp[0] + sp[1] + sp[2] + sp[3];
        float un = fmaxf(sqrtf(s), 1e-15f);
        float t1 = tanhf(un);
        s_g = (t1 > 0.996f) ? (0.996f / un) : (t1 / un);
    }
    __syncthreads();
    float hb = s_g * u;
    hbg[t] = hb;
    float v2 = hb * hb;
    #pragma unroll
    for (int o = 1; o < 64; o <<= 1) v2 += __shfl_xor(v2, o);
    if ((t & 63) == 0) sp[t >> 6] = v2;
    __syncthreads();
    if (t == 0) hbg[256] = sp[0] + sp[1] + sp[2] + sp[3];
}

// ---------------- K1: HypLinear + logmap0 -> xtT (bf16, transposed [D][N]) --
__global__ __launch_bounds__(256) void k1_hyplinear(
    const float* __restrict__ x, const float* __restrict__ W,
    const float* __restrict__ hbg, __hip_bfloat16* __restrict__ xtT)
{
    __shared__ __align__(16) float sx[16][264];   // x tile; later reused for mx
    __shared__ __align__(16) float sw[256][36];   // W k-chunk [d][32]
    __shared__ float s_xn[16], s_P[16], s_Q[16];
    __shared__ float s_hb[256];
    __shared__ float s_b2;

    const int t  = threadIdx.x;
    const int r0 = blockIdx.x * 16;
    const int row = t >> 4;
    const int j16 = (t & 15) * 4;

    {   // stage x tile, coalesced (16 threads/row x 4 float4)
        #pragma unroll
        for (int i = 0; i < 4; i++)
            *(float4*)(&sx[row][j16 + 64 * i]) =
                *(const float4*)(x + (r0 + row) * 256 + j16 + 64 * i);
    }
    s_hb[t] = hbg[t];
    if (t == 0) s_b2 = hbg[256];
    __syncthreads();

    {   // per-row ||x||^2 (strided, <=2-way banks)
        int r = t >> 4, j = t & 15;
        float s2 = 0.f;
        #pragma unroll
        for (int i = 0; i < 16; i++) { float v = sx[r][j + 16 * i]; s2 += v * v; }
        s2 += __shfl_xor(s2, 1); s2 += __shfl_xor(s2, 2);
        s2 += __shfl_xor(s2, 4); s2 += __shfl_xor(s2, 8);
        if (j == 0) s_xn[r] = s2;
    }

    float acc[16];
    #pragma unroll
    for (int r = 0; r < 16; r++) acc[r] = 0.f;

    for (int kc = 0; kc < 8; kc++) {
        __syncthreads();
        {   // stage W chunk [256][32], coalesced
            int c4 = (t & 7) * 4;
            #pragma unroll
            for (int i = 0; i < 8; i++) {
                int d = i * 32 + (t >> 3);
                *(float4*)(&sw[d][c4]) = *(const float4*)(W + d * 256 + kc * 32 + c4);
            }
        }
        __syncthreads();
        #pragma unroll
        for (int kk = 0; kk < 8; kk++) {
            float4 w4 = *(const float4*)(&sw[t][kk * 4]);
            #pragma unroll
            for (int r = 0; r < 16; r++) {
                float4 x4 = *(const float4*)(&sx[r][kc * 32 + kk * 4]);
                acc[r] = fmaf(x4.x, w4.x, acc[r]);
                acc[r] = fmaf(x4.y, w4.y, acc[r]);
                acc[r] = fmaf(x4.z, w4.z, acc[r]);
                acc[r] = fmaf(x4.w, w4.w, acc[r]);
            }
        }
    }
    __syncthreads();
    #pragma unroll
    for (int r = 0; r < 16; r++) sx[r][t] = acc[r];   // reuse sx as mx tile
    __syncthreads();

    {   // per-row sumsq(mx), dot(mx, hb) -> scalar chain -> P, Q
        int r = t >> 4, j = t & 15;
        float s2 = 0.f, dt = 0.f;
        #pragma unroll
        for (int i = 0; i < 16; i++) {
            float v = sx[r][j + 16 * i];
            s2 += v * v;
            dt += v * s_hb[j + 16 * i];
        }
        s2 += __shfl_xor(s2, 1); s2 += __shfl_xor(s2, 2);
        s2 += __shfl_xor(s2, 4); s2 += __shfl_xor(s2, 8);
        dt += __shfl_xor(dt, 1); dt += __shfl_xor(dt, 2);
        dt += __shfl_xor(dt, 4); dt += __shfl_xor(dt, 8);
        if (j == 0) {
            float b2  = s_b2;
            float xn  = fmaxf(sqrtf(s_xn[r]), 1e-15f);
            float mx2 = s2;
            float mxn = fmaxf(sqrtf(mx2), 1e-15f);
            float at = artanh_clip(xn);
            float tt = tanhf(mxn / xn * at);
            float fr = tt / mxn;
            if (tt > 0.996f) fr = 0.996f / mxn;
            float mvn = fminf(tt, 0.996f);
            float x2  = mvn * mvn;
            float xy  = fr * dt;
            float cA  = 1.0f + 2.0f * xy + b2;
            float cB  = 1.0f - x2;
            float den = fmaxf(1.0f + 2.0f * xy + x2 * b2, 1e-15f);
            float P0 = cA * fr / den;
            float Q0 = cB / den;
            float hn = sqrtf(fmaxf(P0 * P0 * mx2 + 2.0f * P0 * Q0 * dt + Q0 * Q0 * b2, 0.0f));
            hn = fmaxf(hn, 1e-15f);
            float pf  = (hn > 0.996f) ? (0.996f / hn) : 1.0f;
            float hnp = fminf(hn, 0.996f);
            float lam = artanh_clip(hnp) / hnp;
            s_P[r] = lam * pf * P0;
            s_Q[r] = lam * pf * Q0;
        }
    }
    __syncthreads();

    {   // xt[r][t] = P[r]*mx[r][t] + Q[r]*hb[t]; write transposed xtT[t][r0+r]
        float hb = s_hb[t];
        unsigned int pk[8];
        #pragma unroll
        for (int r = 0; r < 16; r += 2) {
            float a0 = s_P[r]     * acc[r]     + s_Q[r]     * hb;
            float a1 = s_P[r + 1] * acc[r + 1] + s_Q[r + 1] * hb;
            unsigned int lo = (unsigned int)__bfloat16_as_ushort(__float2bfloat16(a0));
            unsigned int hi = (unsigned int)__bfloat16_as_ushort(__float2bfloat16(a1));
            pk[r >> 1] = lo | (hi << 16);
        }
        uint4* dst = (uint4*)(xtT + t * 8192 + r0);
        dst[0] = make_uint4(pk[0], pk[1], pk[2], pk[3]);
        dst[1] = make_uint4(pk[4], pk[5], pk[6], pk[7]);
    }
}

// ---------------- K2a: barrier-free GEMM  support = adj @ xt ----------------
// grid 256 (1 block/CU), block 512 = 8 waves. BM=32, BN=256; wave owns a
// 32x32 output strip (cols wave*32..+31) and runs the FULL K independently.
// A-frags per-lane direct from global f32 (8x redundant across waves ->
// L1/L2-served); B-frags from L2-resident xtT. 2-deep register pipeline,
// no LDS, no barriers in the loop (drift fence every 16 tiles).
struct TileR {
    float4  a00, a01, a02, a03;   // A rowgrp0: [kw0: +0,+4][kw1: +32,+36]
    float4  a10, a11, a12, a13;   // A rowgrp1
    short8v b00, b01;             // B nfrag0: kw0, kw1
    short8v b10, b11;             // B nfrag1: kw0, kw1
};

__device__ __forceinline__ void tload(TileR& T,
    const float* a0, const float* a1,
    const __hip_bfloat16* b0, const __hip_bfloat16* b1, int k0)
{
    T.a00 = *(const float4*)(a0 + k0);
    T.a01 = *(const float4*)(a0 + k0 + 4);
    T.a02 = *(const float4*)(a0 + k0 + 32);
    T.a03 = *(const float4*)(a0 + k0 + 36);
    T.a10 = *(const float4*)(a1 + k0);
    T.a11 = *(const float4*)(a1 + k0 + 4);
    T.a12 = *(const float4*)(a1 + k0 + 32);
    T.a13 = *(const float4*)(a1 + k0 + 36);
    T.b00 = *(const short8v*)(b0 + k0);
    T.b01 = *(const short8v*)(b0 + k0 + 32);
    T.b10 = *(const short8v*)(b1 + k0);
    T.b11 = *(const short8v*)(b1 + k0 + 32);
}

__device__ __forceinline__ void tconsume(const TileR& T, f32x4 acc[2][2]) {
    short8v am0k0 = cvt8_bf16(T.a00, T.a01);
    short8v am0k1 = cvt8_bf16(T.a02, T.a03);
    short8v am1k0 = cvt8_bf16(T.a10, T.a11);
    short8v am1k1 = cvt8_bf16(T.a12, T.a13);
    acc[0][0] = __builtin_amdgcn_mfma_f32_16x16x32_bf16(am0k0, T.b00, acc[0][0], 0, 0, 0);
    acc[0][1] = __builtin_amdgcn_mfma_f32_16x16x32_bf16(am0k0, T.b10, acc[0][1], 0, 0, 0);
    acc[1][0] = __builtin_amdgcn_mfma_f32_16x16x32_bf16(am1k0, T.b00, acc[1][0], 0, 0, 0);
    acc[1][1] = __builtin_amdgcn_mfma_f32_16x16x32_bf16(am1k0, T.b10, acc[1][1], 0, 0, 0);
    acc[0][0] = __builtin_amdgcn_mfma_f32_16x16x32_bf16(am0k1, T.b01, acc[0][0], 0, 0, 0);
    acc[0][1] = __builtin_amdgcn_mfma_f32_16x16x32_bf16(am0k1, T.b11, acc[0][1], 0, 0, 0);
    acc[1][0] = __builtin_amdgcn_mfma_f32_16x16x32_bf16(am1k1, T.b01, acc[1][0], 0, 0, 0);
    acc[1][1] = __builtin_amdgcn_mfma_f32_16x16x32_bf16(am1k1, T.b11, acc[1][1], 0, 0, 0);
}

__global__ __launch_bounds__(512) void k2_gemm(
    const float* __restrict__ adj,
    const __hip_bfloat16* __restrict__ xtT,
    float* __restrict__ out_h)
{
    const int t    = threadIdx.x;
    const int lane = t & 63;
    const int wave = t >> 6;          // cols wave*32 .. +31
    const int m0   = blockIdx.x * 32;
    const int arow = lane & 15;
    const int g8   = 8 * (lane >> 4);

    const float* aptr0 = adj + (size_t)(m0 + arow) * 8192 + g8;
    const float* aptr1 = aptr0 + (size_t)16 * 8192;
    const __hip_bfloat16* bptr0 = xtT + (size_t)(wave * 32 + arow) * 8192 + g8;
    const __hip_bfloat16* bptr1 = bptr0 + (size_t)16 * 8192;

    f32x4 acc[2][2];
    #pragma unroll
    for (int i = 0; i < 2; i++)
        #pragma unroll
        for (int j = 0; j < 2; j++) acc[i][j] = (f32x4){0.f, 0.f, 0.f, 0.f};

    TileR Ta, Tb;
    tload(Ta, aptr0, aptr1, bptr0, bptr1, 0);

    for (int kt = 0; kt < 128; kt += 2) {
        tload(Tb, aptr0, aptr1, bptr0, bptr1, (kt + 1) * 64);
        tconsume(Ta, acc);
        if (kt + 2 < 128)
            tload(Ta, aptr0, aptr1, bptr0, bptr1, (kt + 2) * 64);
        tconsume(Tb, acc);
        if ((kt & 15) == 14) __syncthreads();   // loose drift fence
    }

    // store support (disjoint; C layout: n=lane&15, m=4*(lane>>4)+q)
    const int crow0 = 4 * (lane >> 4);
    const int ccol  = lane & 15;
    #pragma unroll
    for (int mf = 0; mf < 2; mf++)
        #pragma unroll
        for (int nf = 0; nf < 2; nf++)
            #pragma unroll
            for (int q = 0; q < 4; q++)
                out_h[(m0 + mf * 16 + crow0 + q) * 256 + wave * 32 + nf * 16 + ccol] =
                    acc[mf][nf][q];
}

// ---------------- K2b: pure streaming copy adj -> out_adj -------------------
__global__ __launch_bounds__(256) void k2_copy(
    const float* __restrict__ src, float* __restrict__ dst)
{
    const size_t n = (size_t)N_NODES * N_NODES;
    size_t i = ((size_t)blockIdx.x * 256 + threadIdx.x) * 4;
    const size_t stride = (size_t)gridDim.x * 256 * 4;
    for (; i < n; i += stride) {
        float4 v = *(const float4*)(src + i);
        nt_store4(v, dst + i);
    }
}

// ---------------- K3: in-place epilogue on support (out_h) -------------------
__global__ __launch_bounds__(256) void k3_epilogue(float* __restrict__ h) {
    const int t = threadIdx.x;
    const int r = blockIdx.x * 16 + (t >> 4);
    const int j = t & 15;
    float* p = h + r * 256 + j * 16;

    float4 v[4];
    float s2 = 0.f, sp = 0.f;
    #pragma unroll
    for (int i = 0; i < 4; i++) {
        v[i] = *(const float4*)(p + 4 * i);
        s2 += v[i].x * v[i].x + v[i].y * v[i].y + v[i].z * v[i].z + v[i].w * v[i].w;
        float px = fmaxf(v[i].x, 0.f), py = fmaxf(v[i].y, 0.f);
        float pz = fmaxf(v[i].z, 0.f), pw = fmaxf(v[i].w, 0.f);
        sp += px * px + py * py + pz * pz + pw * pw;
    }
    s2 += __shfl_xor(s2, 1); s2 += __shfl_xor(s2, 2); s2 += __shfl_xor(s2, 4); s2 += __shfl_xor(s2, 8);
    sp += __shfl_xor(sp, 1); sp += __shfl_xor(sp, 2); sp += __shfl_xor(sp, 4); sp += __shfl_xor(sp, 8);

    float ns = fmaxf(sqrtf(s2), 1e-15f);
    float t1 = tanhf(ns);
    float alpha = (t1 > 0.996f) ? (0.996f / ns) : (t1 / ns);   // expmap0+proj
    float nh = fminf(t1, 0.996f);
    float beta = artanh_clip(nh) / nh;                          // logmap0
    float ba = beta * alpha;
    float nxt = fmaxf(ba * sqrtf(sp), 1e-15f);                  // ||relu(xt)||
    float t2 = tanhf(nxt);
    float delta = (t2 > 0.996f) ? (0.996f / nxt) : (t2 / nxt);  // expmap0+proj
    float F = delta * ba;

    #pragma unroll
    for (int i = 0; i < 4; i++) {
        float4 o;
        o.x = F * fmaxf(v[i].x, 0.f);
        o.y = F * fmaxf(v[i].y, 0.f);
        o.z = F * fmaxf(v[i].z, 0.f);
        o.w = F * fmaxf(v[i].w, 0.f);
        *(float4*)(p + 4 * i) = o;
    }
}

extern "C" void kernel_launch(void* const* d_in, const int* in_sizes, int n_in,
                              void* d_out, int out_size, void* d_ws, size_t ws_size,
                              hipStream_t stream)
{
    const float* x    = (const float*)d_in[0];
    const float* adj  = (const float*)d_in[1];
    const float* W    = (const float*)d_in[2];
    const float* bias = (const float*)d_in[3];

    float* out_h   = (float*)d_out;
    float* out_adj = out_h + (size_t)N_NODES * D_DIM;

    __hip_bfloat16* xtT = (__hip_bfloat16*)d_ws;                       // [256][8192] bf16 = 4 MB
    float* hbg = (float*)((char*)d_ws + (size_t)D_DIM * N_NODES * 2);  // hb[256] + b2

    k0_bias<<<1, 256, 0, stream>>>(bias, hbg);
    k1_hyplinear<<<512, 256, 0, stream>>>(x, W, hbg, xtT);
    k2_gemm<<<256, 512, 0, stream>>>(adj, xtT, out_h);
    k3_epilogue<<<512, 256, 0, stream>>>(out_h);
    k2_copy<<<2048, 256, 0, stream>>>(adj, out_adj);
}